// Round 13
// baseline (155.901 us; speedup 1.0000x reference)
//
#include <hip/hip_runtime.h>
#include <hip/hip_bf16.h>

#define NRES 512
#define CZ   128
#define CT   64

typedef short bf16x8 __attribute__((ext_vector_type(8)));
typedef float f32x4  __attribute__((ext_vector_type(4)));

#define MFMA16(a,b,c) __builtin_amdgcn_mfma_f32_16x16x32_bf16((a),(b),(c),0,0,0)

__device__ __forceinline__ unsigned short f2bf(float f){
  __hip_bfloat16 h = __float2bfloat16(f);
  return __builtin_bit_cast(unsigned short, h);
}
__device__ __forceinline__ bf16x8 pack8(const float4 a, const float4 b){
  bf16x8 r;
  r[0]=(short)f2bf(a.x); r[1]=(short)f2bf(a.y); r[2]=(short)f2bf(a.z); r[3]=(short)f2bf(a.w);
  r[4]=(short)f2bf(b.x); r[5]=(short)f2bf(b.y); r[6]=(short)f2bf(b.z); r[7]=(short)f2bf(b.w);
  return r;
}

// 16-lane sum via DPP: xor1, xor2 (quad_perm), half-mirror, mirror. Pure VALU.
template<int CTRL>
__device__ __forceinline__ float dppadd(float x){
  int y = __builtin_amdgcn_update_dpp(0, __builtin_bit_cast(int, x), CTRL, 0xF, 0xF, false);
  return x + __builtin_bit_cast(float, y);
}
__device__ __forceinline__ f32x4 reduce16(f32x4 p){
#pragma unroll
  for (int r = 0; r < 4; ++r){
    float v = p[r];
    v = dppadd<0xB1>(v);
    v = dppadd<0x4E>(v);
    v = dppadd<0x141>(v);
    v = dppadd<0x140>(v);
    p[r] = v;
  }
  return p;
}

// ---- weight pre-pack: B-fragments for mfma_f32_16x16x32_bf16 ----
// frag f: lane l, elem j -> B[k = ks*32 + (l>>4)*8 + j][col = nt*16 + (l&15)]
// f  0..15: wq (128x64), nt=f>>2, ks=f&3, scale=0.25 folded in
// f 16..23: wk (64x64),  nt=(f-16)>>1, ks=(f-16)&1
// f 24..31: wv (64x64),  nt=head=(f-24)>>1, ks=(f-24)&1
// f 32..47: wo (64x128), nt=(f-32)>>1, ks=(f-32)&1
__global__ void prep_pack(const float* __restrict__ wq, const float* __restrict__ wk,
                          const float* __restrict__ wv, const float* __restrict__ wo,
                          unsigned short* __restrict__ packed){
  int idx = blockIdx.x * 256 + threadIdx.x;
  if (idx >= 48 * 64) return;
  int f = idx >> 6, lane = idx & 63;
  const float* W; int Ncols, nt, ks; float scale = 1.0f;
  if (f < 16)      { W = wq; Ncols = 64;  nt = f >> 2;        ks = f & 3;        scale = 0.25f; }
  else if (f < 24) { W = wk; Ncols = 64;  nt = (f - 16) >> 1; ks = (f - 16) & 1; }
  else if (f < 32) { W = wv; Ncols = 64;  nt = (f - 24) >> 1; ks = (f - 24) & 1; }
  else             { W = wo; Ncols = 128; nt = (f - 32) >> 1; ks = (f - 32) & 1; }
  int col = nt * 16 + (lane & 15);
  int k0  = ks * 32 + (lane >> 4) * 8;
  unsigned short* dst = packed + (size_t)f * 512 + (size_t)lane * 8;
#pragma unroll
  for (int j = 0; j < 8; ++j)
    dst[j] = f2bf(W[(k0 + j) * Ncols + col] * scale);
}

// DMA-stage one 32-px t-tile (4 slabs x 8KB f32) into LDS buffer `buf`.
// Global source is PRE-SWIZZLED (16B-chunk col ^= row&7, an involution) so the
// frag reads below can use the same XOR and stay bank-conflict-free (rule:
// swizzle both sides or neither; global_load_lds dst must be linear+lane*16).
__device__ __forceinline__ void stage_tile(const float* __restrict__ t, char* smem,
                                           int buf, int tk, int tid){
  const int i  = tk >> 4;
  const int j0 = (tk & 15) << 5;
#pragma unroll
  for (int s = 0; s < 4; ++s){
    const float* slab = t + (((size_t)s * NRES + i) * NRES + j0) * CT;
    char* dstbase = smem + buf * 32768 + s * 8192;
#pragma unroll
    for (int it = 0; it < 4; ++it){
      int c   = it * 128 + tid;           // chunk 0..511 (16B units)
      int row = c >> 4, col = c & 15;
      const float* src = slab + row * 64 + ((col ^ (row & 7)) << 2);
      __builtin_amdgcn_global_load_lds(reinterpret_cast<const uint4*>(src),
                                       reinterpret_cast<uint4*>(dstbase + (c << 4)),
                                       16, 0, 0);
    }
  }
}

// Block = 128 threads (2 waves), 16 tiles of 32 px (grid 512 = 2 blocks/CU).
// Pipeline per tile: [barrier: buf[cur] staged] -> z loads -> STAGE(k+1 ->
// buf[cur^1]) -> convert frags -> phases A/B/C -> loop. The k+1 staging stays
// in flight across tile k's entire compute (drained only by the next top
// barrier) -> ~32KB continuously outstanding per block vs the old 576B burst.
// Weights: ALL 48 B-frags in registers (192 VGPR; LDS already caps us at
// 1 wave/SIMD so launch_bounds(128,1) gives the full 512-reg budget).
// LDS (69632 B): [0,65536) t double-buffer (2 x 4 slabs x 8KB, chunk-swizzled);
//                [65536,69632) per-wave O buffers (w*2048, R9 layout).
__global__ void __launch_bounds__(128, 1)
tpa_main(const float* __restrict__ t, const float* __restrict__ z,
         const float* __restrict__ mask, const float* __restrict__ bo,
         const unsigned short* __restrict__ packed,
         float* __restrict__ out){
  __shared__ __align__(16) char smem[69632];

  const int tid  = threadIdx.x;
  const int lane = tid & 63;
  const int w    = tid >> 6;         // wave 0..1 -> rows [16w,16w+16) of the 32-px tile
  const int cl   = lane & 15;        // A-frag row / C-frag col
  const int g    = lane >> 4;        // k-subgroup / C-frag row-group
  const int b    = blockIdx.x;

  // -------- stage tile 0 into buf 0 (flies under weight-reg loads) --------
  stage_tile(t, smem, 0, b * 16 + 0, tid);

  // -------- all 48 weight B-frags -> registers (16B each) --------
  bf16x8 wqr[16], wkr[8], wvr[8], wor[16];
#pragma unroll
  for (int f = 0; f < 16; ++f)
    wqr[f] = *reinterpret_cast<const bf16x8*>(packed + (size_t)f * 512 + (size_t)lane * 8);
#pragma unroll
  for (int f = 0; f < 8; ++f)
    wkr[f] = *reinterpret_cast<const bf16x8*>(packed + (size_t)(16 + f) * 512 + (size_t)lane * 8);
#pragma unroll
  for (int f = 0; f < 8; ++f)
    wvr[f] = *reinterpret_cast<const bf16x8*>(packed + (size_t)(24 + f) * 512 + (size_t)lane * 8);
#pragma unroll
  for (int f = 0; f < 16; ++f)
    wor[f] = *reinterpret_cast<const bf16x8*>(packed + (size_t)(32 + f) * 512 + (size_t)lane * 8);

  const float m0 = mask[0], m1 = mask[1], m2 = mask[2], m3 = mask[3];
  const float msum = m0 + m1 + m2 + m3;
  const float gate = (msum > 0.0f) ? 1.0f : 0.0f;
  const float bias[4] = {1e9f * (m0 - 1.0f), 1e9f * (m1 - 1.0f),
                         1e9f * (m2 - 1.0f), 1e9f * (m3 - 1.0f)};
  float bov[8];
#pragma unroll
  for (int nt = 0; nt < 8; ++nt) bov[nt] = bo[nt * 16 + cl];

  unsigned short* o_ws = reinterpret_cast<unsigned short*>(smem + 65536 + w * 2048);
  const int rowi = w * 16 + cl;      // this lane's row within the 32-px tile
  const int rs   = rowi & 7;

#pragma unroll 1
  for (int k = 0; k < 16; ++k){
    const int cur = k & 1;
    __syncthreads();                 // buf[cur] staged; prev tile's stores drained

    const int tk = b * 16 + k;
    const int i  = tk >> 4;
    const int j0 = (tk & 15) << 5;
    const int grow = j0 + rowi;

    // z loads for this tile (latency hides under t-convert)
    const float4* zp = reinterpret_cast<const float4*>(z + ((size_t)i * NRES + grow) * CZ);
    float4 zr[8];
#pragma unroll
    for (int ks = 0; ks < 4; ++ks){
      zr[ks * 2 + 0] = zp[ks * 8 + g * 2 + 0];
      zr[ks * 2 + 1] = zp[ks * 8 + g * 2 + 1];
    }

    // issue next tile's staging NOW — in flight across this tile's compute
    if (k < 15) stage_tile(t, smem, cur ^ 1, tk + 1, tid);

    // convert t frags from buf[cur] (swizzled reads: 2-way conflicts only)
    bf16x8 ta[4][2];
#pragma unroll
    for (int s = 0; s < 4; ++s){
      const char* base = smem + cur * 32768 + s * 8192 + rowi * 256;
#pragma unroll
      for (int ks = 0; ks < 2; ++ks){
        int c0 = ks * 8 + g * 2;
        float4 lo = *reinterpret_cast<const float4*>(base + ((c0 ^ rs) << 4));
        float4 hi = *reinterpret_cast<const float4*>(base + (((c0 + 1) ^ rs) << 4));
        ta[s][ks] = pack8(lo, hi);
      }
    }
    bf16x8 za[4];
#pragma unroll
    for (int ks = 0; ks < 4; ++ks) za[ks] = pack8(zr[ks * 2], zr[ks * 2 + 1]);

    // -------- phase A: Q for all 4 heads --------
    f32x4 qf[4];
#pragma unroll
    for (int h = 0; h < 4; ++h){
      f32x4 q = {0.f, 0.f, 0.f, 0.f};
#pragma unroll
      for (int ks = 0; ks < 4; ++ks) q = MFMA16(za[ks], wqr[h * 4 + ks], q);
      qf[h] = q;
    }

    // -------- phase B: per head K-logits, softmax, V combine; O -> LDS --------
#pragma unroll
    for (int h = 0; h < 4; ++h){
      f32x4 lgh[4];
#pragma unroll
      for (int s = 0; s < 4; ++s){
        f32x4 acc = {0.f, 0.f, 0.f, 0.f};
        acc = MFMA16(ta[s][0], wkr[h * 2 + 0], acc);
        acc = MFMA16(ta[s][1], wkr[h * 2 + 1], acc);
        f32x4 p = reduce16(acc * qf[h]);
#pragma unroll
        for (int r = 0; r < 4; ++r) p[r] += bias[s];
        lgh[s] = p;
      }
      f32x4 mx, sum = {0.f, 0.f, 0.f, 0.f};
#pragma unroll
      for (int r = 0; r < 4; ++r)
        mx[r] = fmaxf(fmaxf(lgh[0][r], lgh[1][r]), fmaxf(lgh[2][r], lgh[3][r]));
#pragma unroll
      for (int s = 0; s < 4; ++s){
#pragma unroll
        for (int r = 0; r < 4; ++r) lgh[s][r] = __expf(lgh[s][r] - mx[r]);
        sum += lgh[s];
      }
      f32x4 inv;
#pragma unroll
      for (int r = 0; r < 4; ++r) inv[r] = 1.0f / sum[r];
#pragma unroll
      for (int s = 0; s < 4; ++s) lgh[s] *= inv;

      f32x4 of = {0.f, 0.f, 0.f, 0.f};
#pragma unroll
      for (int s = 0; s < 4; ++s){
        f32x4 vacc = {0.f, 0.f, 0.f, 0.f};
        vacc = MFMA16(ta[s][0], wvr[h * 2 + 0], vacc);
        vacc = MFMA16(ta[s][1], wvr[h * 2 + 1], vacc);
        of += lgh[s] * vacc;
      }
#pragma unroll
      for (int r = 0; r < 4; ++r){
        int row = (g << 2) + r;
        o_ws[row * 64 + ((h * 16 + cl) ^ ((row & 7) << 3))] = (unsigned short)f2bf(of[r]);
      }
    }
    asm volatile("s_waitcnt lgkmcnt(0)" ::: "memory");   // wave-private O complete

    // -------- phase C: out = O @ wo + bo, gated --------
    bf16x8 oa[2];
#pragma unroll
    for (int ks = 0; ks < 2; ++ks)
      oa[ks] = *reinterpret_cast<const bf16x8*>(
          o_ws + cl * 64 + ((ks * 32 + g * 8) ^ ((cl & 7) << 3)));

    float* outg = out + ((size_t)i * NRES + j0 + (w << 4)) * CZ;
#pragma unroll
    for (int nt = 0; nt < 8; ++nt){
      f32x4 acc = {0.f, 0.f, 0.f, 0.f};
      acc = MFMA16(oa[0], wor[nt * 2 + 0], acc);
      acc = MFMA16(oa[1], wor[nt * 2 + 1], acc);
      int col = nt * 16 + cl;
#pragma unroll
      for (int r = 0; r < 4; ++r)
        outg[(size_t)((g << 2) + r) * CZ + col] = (acc[r] + bov[nt]) * gate;
    }
  }
}

extern "C" void kernel_launch(void* const* d_in, const int* in_sizes, int n_in,
                              void* d_out, int out_size, void* d_ws, size_t ws_size,
                              hipStream_t stream) {
  const float* t    = (const float*)d_in[0];
  const float* z    = (const float*)d_in[1];
  const float* mask = (const float*)d_in[2];
  const float* wq   = (const float*)d_in[3];
  const float* wk   = (const float*)d_in[4];
  const float* wv   = (const float*)d_in[5];
  const float* wo   = (const float*)d_in[6];
  const float* bo   = (const float*)d_in[7];
  unsigned short* packed = (unsigned short*)d_ws;

  hipLaunchKernelGGL(prep_pack, dim3(12), dim3(256), 0, stream, wq, wk, wv, wo, packed);
  hipLaunchKernelGGL(tpa_main, dim3(512), dim3(128), 0, stream,
                     t, z, mask, bo, packed, (float*)d_out);
}

// Round 14
// 119.441 us; speedup vs baseline: 1.3053x; 1.3053x over previous
//
#include <hip/hip_runtime.h>
#include <hip/hip_bf16.h>

#define NRES 512
#define CZ   128
#define CT   64

typedef short bf16x8 __attribute__((ext_vector_type(8)));
typedef float f32x4  __attribute__((ext_vector_type(4)));

#define MFMA16(a,b,c) __builtin_amdgcn_mfma_f32_16x16x32_bf16((a),(b),(c),0,0,0)

__device__ __forceinline__ unsigned short f2bf(float f){
  __hip_bfloat16 h = __float2bfloat16(f);
  return __builtin_bit_cast(unsigned short, h);
}
__device__ __forceinline__ bf16x8 pack8(const float4 a, const float4 b){
  bf16x8 r;
  r[0]=(short)f2bf(a.x); r[1]=(short)f2bf(a.y); r[2]=(short)f2bf(a.z); r[3]=(short)f2bf(a.w);
  r[4]=(short)f2bf(b.x); r[5]=(short)f2bf(b.y); r[6]=(short)f2bf(b.z); r[7]=(short)f2bf(b.w);
  return r;
}

// 16-lane sum via DPP: xor1, xor2 (quad_perm), half-mirror, mirror. Pure VALU.
template<int CTRL>
__device__ __forceinline__ float dppadd(float x){
  int y = __builtin_amdgcn_update_dpp(0, __builtin_bit_cast(int, x), CTRL, 0xF, 0xF, false);
  return x + __builtin_bit_cast(float, y);
}
__device__ __forceinline__ f32x4 reduce16(f32x4 p){
#pragma unroll
  for (int r = 0; r < 4; ++r){
    float v = p[r];
    v = dppadd<0xB1>(v);
    v = dppadd<0x4E>(v);
    v = dppadd<0x141>(v);
    v = dppadd<0x140>(v);
    p[r] = v;
  }
  return p;
}

// ---- weight pre-pack: B-fragments for mfma_f32_16x16x32_bf16 ----
// frag f: lane l, elem j -> B[k = ks*32 + (l>>4)*8 + j][col = nt*16 + (l&15)]
// f  0..15: wq (128x64), nt=f>>2, ks=f&3, scale=0.25 folded in
// f 16..23: wk (64x64),  nt=(f-16)>>1, ks=(f-16)&1
// f 24..31: wv (64x64),  nt=head=(f-24)>>1, ks=(f-24)&1
// f 32..47: wo (64x128), nt=(f-32)>>1, ks=(f-32)&1
__global__ void prep_pack(const float* __restrict__ wq, const float* __restrict__ wk,
                          const float* __restrict__ wv, const float* __restrict__ wo,
                          unsigned short* __restrict__ packed){
  int idx = blockIdx.x * 256 + threadIdx.x;
  if (idx >= 48 * 64) return;
  int f = idx >> 6, lane = idx & 63;
  const float* W; int Ncols, nt, ks; float scale = 1.0f;
  if (f < 16)      { W = wq; Ncols = 64;  nt = f >> 2;        ks = f & 3;        scale = 0.25f; }
  else if (f < 24) { W = wk; Ncols = 64;  nt = (f - 16) >> 1; ks = (f - 16) & 1; }
  else if (f < 32) { W = wv; Ncols = 64;  nt = (f - 24) >> 1; ks = (f - 24) & 1; }
  else             { W = wo; Ncols = 128; nt = (f - 32) >> 1; ks = (f - 32) & 1; }
  int col = nt * 16 + (lane & 15);
  int k0  = ks * 32 + (lane >> 4) * 8;
  unsigned short* dst = packed + (size_t)f * 512 + (size_t)lane * 8;
#pragma unroll
  for (int j = 0; j < 8; ++j)
    dst[j] = f2bf(W[(k0 + j) * Ncols + col] * scale);
}

// Block = 256 threads (4 waves), 64 pixels of row i. R12 champion per-wave code;
// geometry change only: LDS weight stage shrunk to wk/wv/wo (32KB, frags 16..47),
// wq streamed ONCE direct L2->regs pre-barrier (one-shot, not R4's in-loop
// re-reads). o_ws gets its own region -> second barrier eliminated.
// LDS (40960 B): [0,32768) 32 frags: wk f0..7, wv f8..15, wo f16..31 (f*1024 +
// lane*16, linear); [32768,40960) per-wave O buffers (w*2048, R9 swz layout).
// 4 blocks/CU (163840 B = exactly 160KB), 16 waves/CU in 4 INDEPENDENT barrier
// domains (R5 had 12/3, R7 16/2 — domains never scaled before).
// waves_per_eu(4,4): VGPR cap 128; R12 prologue peaked ~116 -> no spill.
__global__ void __launch_bounds__(256)
__attribute__((amdgpu_waves_per_eu(4, 4)))
tpa_main(const float* __restrict__ t, const float* __restrict__ z,
         const float* __restrict__ mask, const float* __restrict__ bo,
         const unsigned short* __restrict__ packed,
         float* __restrict__ out){
  __shared__ __align__(16) char smem[40960];

  const int tid  = threadIdx.x;
  const int lane = tid & 63;
  const int w    = tid >> 6;         // wave 0..3 -> rows [16w,16w+16) of the tile
  const int cl   = lane & 15;        // A-frag row / C-frag col
  const int g    = lane >> 4;        // k-subgroup / C-frag row-group
  const int b    = blockIdx.x;
  const int i    = b >> 3;           // z-row
  const int j0   = (b & 7) << 6;     // pixel-column tile base
  const int r0   = j0 + (w << 4);    // wave's first global pixel row
  const int grow = r0 + cl;          // this lane's A-frag global row

  // -------- stage wk/wv/wo frags (32KB = packed frags 16..47) -> LDS, async ----
#pragma unroll
  for (int it = 0; it < 8; ++it){
    int idx = it * 256 + tid;
    __builtin_amdgcn_global_load_lds(
        reinterpret_cast<const uint4*>(packed) + 1024 + idx,
        reinterpret_cast<uint4*>(smem) + idx, 16, 0, 0);
  }

  // -------- issue ALL 24 input loads into named registers (one round trip) ----
  const float4* zp = reinterpret_cast<const float4*>(z + ((size_t)i * NRES + grow) * CZ);
  float4 zr0 = zp[0*8 + g*2 + 0], zr1 = zp[0*8 + g*2 + 1];
  float4 zr2 = zp[1*8 + g*2 + 0], zr3 = zp[1*8 + g*2 + 1];
  float4 zr4 = zp[2*8 + g*2 + 0], zr5 = zp[2*8 + g*2 + 1];
  float4 zr6 = zp[3*8 + g*2 + 0], zr7 = zp[3*8 + g*2 + 1];

  const float4* tp0 = reinterpret_cast<const float4*>(t + (((size_t)0 * NRES + i) * NRES + grow) * CT);
  const float4* tp1 = reinterpret_cast<const float4*>(t + (((size_t)1 * NRES + i) * NRES + grow) * CT);
  const float4* tp2 = reinterpret_cast<const float4*>(t + (((size_t)2 * NRES + i) * NRES + grow) * CT);
  const float4* tp3 = reinterpret_cast<const float4*>(t + (((size_t)3 * NRES + i) * NRES + grow) * CT);
  float4 t00 = tp0[g*2+0], t01 = tp0[g*2+1], t02 = tp0[8+g*2+0], t03 = tp0[8+g*2+1];
  float4 t10 = tp1[g*2+0], t11 = tp1[g*2+1], t12 = tp1[8+g*2+0], t13 = tp1[8+g*2+1];
  float4 t20 = tp2[g*2+0], t21 = tp2[g*2+1], t22 = tp2[8+g*2+0], t23 = tp2[8+g*2+1];
  float4 t30 = tp3[g*2+0], t31 = tp3[g*2+1], t32 = tp3[8+g*2+0], t33 = tp3[8+g*2+1];

  // -------- convert to bf16 fragments (raw regs die here) --------
  bf16x8 za[4];
  za[0] = pack8(zr0, zr1); za[1] = pack8(zr2, zr3);
  za[2] = pack8(zr4, zr5); za[3] = pack8(zr6, zr7);
  bf16x8 ta[4][2];
  ta[0][0] = pack8(t00, t01); ta[0][1] = pack8(t02, t03);
  ta[1][0] = pack8(t10, t11); ta[1][1] = pack8(t12, t13);
  ta[2][0] = pack8(t20, t21); ta[2][1] = pack8(t22, t23);
  ta[3][0] = pack8(t30, t31); ta[3][1] = pack8(t32, t33);

  // -------- wq frags: one-shot L2->reg stream (raws are dead; 32 regs) --------
  bf16x8 wqf[16];
#pragma unroll
  for (int f = 0; f < 16; ++f)
    wqf[f] = *reinterpret_cast<const bf16x8*>(packed + (size_t)f * 512 + (size_t)lane * 8);

  const float m0 = mask[0], m1 = mask[1], m2 = mask[2], m3 = mask[3];
  const float msum = m0 + m1 + m2 + m3;
  const float gate = (msum > 0.0f) ? 1.0f : 0.0f;
  const float bias[4] = {1e9f * (m0 - 1.0f), 1e9f * (m1 - 1.0f),
                         1e9f * (m2 - 1.0f), 1e9f * (m3 - 1.0f)};

  __syncthreads();   // weight LDS visible; the ONLY barrier in the kernel

// fi: 0..7 = wk, 8..15 = wv, 16..31 = wo
#define LDB(fi) (*reinterpret_cast<const bf16x8*>(smem + (size_t)(fi) * 1024 + (size_t)lane * 16))

  // -------- phase A: Q for all 4 heads (wq from registers) --------
  f32x4 qf[4];
#pragma unroll
  for (int h = 0; h < 4; ++h){
    f32x4 q = {0.f, 0.f, 0.f, 0.f};
#pragma unroll
    for (int ks = 0; ks < 4; ++ks) q = MFMA16(za[ks], wqf[h * 4 + ks], q);
    qf[h] = q;
  }

  unsigned short* o_ws = reinterpret_cast<unsigned short*>(smem + 32768 + w * 2048);

  // -------- phase B: per head K-logits, softmax, V combine (C-layout) --------
#pragma unroll
  for (int h = 0; h < 4; ++h){
    f32x4 lgh[4];
#pragma unroll
    for (int s = 0; s < 4; ++s){
      f32x4 acc = {0.f, 0.f, 0.f, 0.f};
      acc = MFMA16(ta[s][0], LDB(h * 2 + 0), acc);
      acc = MFMA16(ta[s][1], LDB(h * 2 + 1), acc);
      f32x4 p = reduce16(acc * qf[h]);
#pragma unroll
      for (int r = 0; r < 4; ++r) p[r] += bias[s];
      lgh[s] = p;
    }
    f32x4 mx, sum = {0.f, 0.f, 0.f, 0.f};
#pragma unroll
    for (int r = 0; r < 4; ++r)
      mx[r] = fmaxf(fmaxf(lgh[0][r], lgh[1][r]), fmaxf(lgh[2][r], lgh[3][r]));
#pragma unroll
    for (int s = 0; s < 4; ++s){
#pragma unroll
      for (int r = 0; r < 4; ++r) lgh[s][r] = __expf(lgh[s][r] - mx[r]);
      sum += lgh[s];
    }
    f32x4 inv;
#pragma unroll
    for (int r = 0; r < 4; ++r) inv[r] = 1.0f / sum[r];
#pragma unroll
    for (int s = 0; s < 4; ++s) lgh[s] *= inv;

    // O = sum_s a_s * (t_s @ wv_h), combined on C-fragments
    f32x4 of = {0.f, 0.f, 0.f, 0.f};
#pragma unroll
    for (int s = 0; s < 4; ++s){
      f32x4 vacc = {0.f, 0.f, 0.f, 0.f};
      vacc = MFMA16(ta[s][0], LDB(8 + h * 2 + 0), vacc);
      vacc = MFMA16(ta[s][1], LDB(8 + h * 2 + 1), vacc);
      of += lgh[s] * vacc;
    }
#pragma unroll
    for (int r = 0; r < 4; ++r){
      int row = (g << 2) + r;
      o_ws[row * 64 + ((h * 16 + cl) ^ ((row & 7) << 3))] = (unsigned short)f2bf(of[r]);
    }
  }
  asm volatile("s_waitcnt lgkmcnt(0)" ::: "memory");   // wave-private O complete

  // -------- phase C: out = O @ wo + bo, gated; direct f32 stores --------
  {
    bf16x8 oa[2];
#pragma unroll
    for (int ks = 0; ks < 2; ++ks)
      oa[ks] = *reinterpret_cast<const bf16x8*>(
          o_ws + cl * 64 + ((ks * 32 + g * 8) ^ ((cl & 7) << 3)));

    float* outg = out + ((size_t)i * NRES + r0) * CZ;
#pragma unroll
    for (int nt = 0; nt < 8; ++nt){
      f32x4 acc = {0.f, 0.f, 0.f, 0.f};
      acc = MFMA16(oa[0], LDB(16 + nt * 2 + 0), acc);
      acc = MFMA16(oa[1], LDB(16 + nt * 2 + 1), acc);
      int col = nt * 16 + cl;
      float bov = bo[col];
#pragma unroll
      for (int r = 0; r < 4; ++r)
        outg[(size_t)((g << 2) + r) * CZ + col] = (acc[r] + bov) * gate;
    }
  }
}

extern "C" void kernel_launch(void* const* d_in, const int* in_sizes, int n_in,
                              void* d_out, int out_size, void* d_ws, size_t ws_size,
                              hipStream_t stream) {
  const float* t    = (const float*)d_in[0];
  const float* z    = (const float*)d_in[1];
  const float* mask = (const float*)d_in[2];
  const float* wq   = (const float*)d_in[3];
  const float* wk   = (const float*)d_in[4];
  const float* wv   = (const float*)d_in[5];
  const float* wo   = (const float*)d_in[6];
  const float* bo   = (const float*)d_in[7];
  unsigned short* packed = (unsigned short*)d_ws;

  hipLaunchKernelGGL(prep_pack, dim3(12), dim3(256), 0, stream, wq, wk, wv, wo, packed);
  hipLaunchKernelGGL(tpa_main, dim3(4096), dim3(256), 0, stream,
                     t, z, mask, bo, packed, (float*)d_out);
}

// Round 15
// 110.811 us; speedup vs baseline: 1.4069x; 1.0779x over previous
//
#include <hip/hip_runtime.h>
#include <hip/hip_bf16.h>

#define NRES 512
#define CZ   128
#define CT   64

typedef short bf16x8 __attribute__((ext_vector_type(8)));
typedef float f32x4  __attribute__((ext_vector_type(4)));

#define MFMA16(a,b,c) __builtin_amdgcn_mfma_f32_16x16x32_bf16((a),(b),(c),0,0,0)

__device__ __forceinline__ unsigned short f2bf(float f){
  __hip_bfloat16 h = __float2bfloat16(f);
  return __builtin_bit_cast(unsigned short, h);
}
__device__ __forceinline__ bf16x8 pack8(const float4 a, const float4 b){
  bf16x8 r;
  r[0]=(short)f2bf(a.x); r[1]=(short)f2bf(a.y); r[2]=(short)f2bf(a.z); r[3]=(short)f2bf(a.w);
  r[4]=(short)f2bf(b.x); r[5]=(short)f2bf(b.y); r[6]=(short)f2bf(b.z); r[7]=(short)f2bf(b.w);
  return r;
}

// 16-lane sum via DPP: xor1, xor2 (quad_perm), half-mirror, mirror. Pure VALU.
template<int CTRL>
__device__ __forceinline__ float dppadd(float x){
  int y = __builtin_amdgcn_update_dpp(0, __builtin_bit_cast(int, x), CTRL, 0xF, 0xF, false);
  return x + __builtin_bit_cast(float, y);
}
__device__ __forceinline__ f32x4 reduce16(f32x4 p){
#pragma unroll
  for (int r = 0; r < 4; ++r){
    float v = p[r];
    v = dppadd<0xB1>(v);
    v = dppadd<0x4E>(v);
    v = dppadd<0x141>(v);
    v = dppadd<0x140>(v);
    p[r] = v;
  }
  return p;
}

// ---- weight pre-pack: B-fragments for mfma_f32_16x16x32_bf16 ----
// frag f: lane l, elem j -> B[k = ks*32 + (l>>4)*8 + j][col = nt*16 + (l&15)]
// f  0..15: wq (128x64), nt=f>>2, ks=f&3, scale=0.25 folded in
// f 16..23: wk (64x64),  nt=(f-16)>>1, ks=(f-16)&1
// f 24..31: wv (64x64),  nt=head=(f-24)>>1, ks=(f-24)&1
// f 32..47: wo (64x128), nt=(f-32)>>1, ks=(f-32)&1
__global__ void prep_pack(const float* __restrict__ wq, const float* __restrict__ wk,
                          const float* __restrict__ wv, const float* __restrict__ wo,
                          unsigned short* __restrict__ packed){
  int idx = blockIdx.x * 256 + threadIdx.x;
  if (idx >= 48 * 64) return;
  int f = idx >> 6, lane = idx & 63;
  const float* W; int Ncols, nt, ks; float scale = 1.0f;
  if (f < 16)      { W = wq; Ncols = 64;  nt = f >> 2;        ks = f & 3;        scale = 0.25f; }
  else if (f < 24) { W = wk; Ncols = 64;  nt = (f - 16) >> 1; ks = (f - 16) & 1; }
  else if (f < 32) { W = wv; Ncols = 64;  nt = (f - 24) >> 1; ks = (f - 24) & 1; }
  else             { W = wo; Ncols = 128; nt = (f - 32) >> 1; ks = (f - 32) & 1; }
  int col = nt * 16 + (lane & 15);
  int k0  = ks * 32 + (lane >> 4) * 8;
  unsigned short* dst = packed + (size_t)f * 512 + (size_t)lane * 8;
#pragma unroll
  for (int j = 0; j < 8; ++j)
    dst[j] = f2bf(W[(k0 + j) * Ncols + col] * scale);
}

// R12 champion (110.4us), restored as final kernel, with ONE ordering tweak:
// the 24 latency-critical input loads issue BEFORE the async weight-staging
// DMAs (input loads gate the converts/barrier arrival; staging is only
// consumed at the barrier, so it can fill the pipe behind them).
// Block = 256 threads (4 waves), 64 pixels of row i.
// amdgpu_waves_per_eu(3,3) pins the allocator at the occupancy LDS already
// enforces (3 blocks/CU) -> ~170 VGPR budget; all 24 input float4s in named
// registers -> all loads in flight at once, one HBM round trip per wave.
// LDS (49152 B): [0,49152) 48 weight B-frags (frag f at f*1024, lane at *16);
// after phase A the dead wq region [0,8192) holds per-wave O buffers (w*2048).
__global__ void __launch_bounds__(256)
__attribute__((amdgpu_waves_per_eu(3, 3)))
tpa_main(const float* __restrict__ t, const float* __restrict__ z,
         const float* __restrict__ mask, const float* __restrict__ bo,
         const unsigned short* __restrict__ packed,
         float* __restrict__ out){
  __shared__ __align__(16) char smem[49152];

  const int tid  = threadIdx.x;
  const int lane = tid & 63;
  const int w    = tid >> 6;         // wave 0..3 -> rows [16w,16w+16) of the tile
  const int cl   = lane & 15;        // A-frag row / C-frag col
  const int g    = lane >> 4;        // k-subgroup / C-frag row-group
  const int b    = blockIdx.x;
  const int i    = b >> 3;           // z-row
  const int j0   = (b & 7) << 6;     // pixel-column tile base
  const int r0   = j0 + (w << 4);    // wave's first global pixel row
  const int grow = r0 + cl;          // this lane's A-frag global row

  // -------- issue ALL 24 input loads into named registers FIRST --------
  const float4* zp = reinterpret_cast<const float4*>(z + ((size_t)i * NRES + grow) * CZ);
  float4 zr0 = zp[0*8 + g*2 + 0], zr1 = zp[0*8 + g*2 + 1];
  float4 zr2 = zp[1*8 + g*2 + 0], zr3 = zp[1*8 + g*2 + 1];
  float4 zr4 = zp[2*8 + g*2 + 0], zr5 = zp[2*8 + g*2 + 1];
  float4 zr6 = zp[3*8 + g*2 + 0], zr7 = zp[3*8 + g*2 + 1];

  const float4* tp0 = reinterpret_cast<const float4*>(t + (((size_t)0 * NRES + i) * NRES + grow) * CT);
  const float4* tp1 = reinterpret_cast<const float4*>(t + (((size_t)1 * NRES + i) * NRES + grow) * CT);
  const float4* tp2 = reinterpret_cast<const float4*>(t + (((size_t)2 * NRES + i) * NRES + grow) * CT);
  const float4* tp3 = reinterpret_cast<const float4*>(t + (((size_t)3 * NRES + i) * NRES + grow) * CT);
  float4 t00 = tp0[g*2+0], t01 = tp0[g*2+1], t02 = tp0[8+g*2+0], t03 = tp0[8+g*2+1];
  float4 t10 = tp1[g*2+0], t11 = tp1[g*2+1], t12 = tp1[8+g*2+0], t13 = tp1[8+g*2+1];
  float4 t20 = tp2[g*2+0], t21 = tp2[g*2+1], t22 = tp2[8+g*2+0], t23 = tp2[8+g*2+1];
  float4 t30 = tp3[g*2+0], t31 = tp3[g*2+1], t32 = tp3[8+g*2+0], t33 = tp3[8+g*2+1];

  // -------- stage all 48 weight frags (48KB) global -> LDS, async, behind ----
#pragma unroll
  for (int it = 0; it < 12; ++it){
    int idx = it * 256 + tid;
    __builtin_amdgcn_global_load_lds(
        reinterpret_cast<const uint4*>(packed) + idx,
        reinterpret_cast<uint4*>(smem) + idx, 16, 0, 0);
  }

  // -------- convert to bf16 fragments (raw regs die here) --------
  bf16x8 za[4];
  za[0] = pack8(zr0, zr1); za[1] = pack8(zr2, zr3);
  za[2] = pack8(zr4, zr5); za[3] = pack8(zr6, zr7);
  bf16x8 ta[4][2];
  ta[0][0] = pack8(t00, t01); ta[0][1] = pack8(t02, t03);
  ta[1][0] = pack8(t10, t11); ta[1][1] = pack8(t12, t13);
  ta[2][0] = pack8(t20, t21); ta[2][1] = pack8(t22, t23);
  ta[3][0] = pack8(t30, t31); ta[3][1] = pack8(t32, t33);

  const float m0 = mask[0], m1 = mask[1], m2 = mask[2], m3 = mask[3];
  const float msum = m0 + m1 + m2 + m3;
  const float gate = (msum > 0.0f) ? 1.0f : 0.0f;
  const float bias[4] = {1e9f * (m0 - 1.0f), 1e9f * (m1 - 1.0f),
                         1e9f * (m2 - 1.0f), 1e9f * (m3 - 1.0f)};

  __syncthreads();   // weight LDS visible

#define LDB(fi) (*reinterpret_cast<const bf16x8*>(smem + (size_t)(fi) * 1024 + (size_t)lane * 16))

  // -------- phase A: Q for all 4 heads (consumes wq frags 0..15) --------
  f32x4 qf[4];
#pragma unroll
  for (int h = 0; h < 4; ++h){
    f32x4 q = {0.f, 0.f, 0.f, 0.f};
#pragma unroll
    for (int ks = 0; ks < 4; ++ks) q = MFMA16(za[ks], LDB(h * 4 + ks), q);
    qf[h] = q;
  }

  __syncthreads();   // all waves done with wq; O may overlay [0,8192)

  unsigned short* o_ws = reinterpret_cast<unsigned short*>(smem + w * 2048);

  // -------- phase B: per head K-logits, softmax, V combine (C-layout) --------
#pragma unroll
  for (int h = 0; h < 4; ++h){
    f32x4 lgh[4];
#pragma unroll
    for (int s = 0; s < 4; ++s){
      f32x4 acc = {0.f, 0.f, 0.f, 0.f};
      acc = MFMA16(ta[s][0], LDB(16 + h * 2 + 0), acc);
      acc = MFMA16(ta[s][1], LDB(16 + h * 2 + 1), acc);
      f32x4 p = reduce16(acc * qf[h]);
#pragma unroll
      for (int r = 0; r < 4; ++r) p[r] += bias[s];
      lgh[s] = p;
    }
    f32x4 mx, sum = {0.f, 0.f, 0.f, 0.f};
#pragma unroll
    for (int r = 0; r < 4; ++r)
      mx[r] = fmaxf(fmaxf(lgh[0][r], lgh[1][r]), fmaxf(lgh[2][r], lgh[3][r]));
#pragma unroll
    for (int s = 0; s < 4; ++s){
#pragma unroll
      for (int r = 0; r < 4; ++r) lgh[s][r] = __expf(lgh[s][r] - mx[r]);
      sum += lgh[s];
    }
    f32x4 inv;
#pragma unroll
    for (int r = 0; r < 4; ++r) inv[r] = 1.0f / sum[r];
#pragma unroll
    for (int s = 0; s < 4; ++s) lgh[s] *= inv;

    // O = sum_s a_s * (t_s @ wv_h), combined on C-fragments
    f32x4 of = {0.f, 0.f, 0.f, 0.f};
#pragma unroll
    for (int s = 0; s < 4; ++s){
      f32x4 vacc = {0.f, 0.f, 0.f, 0.f};
      vacc = MFMA16(ta[s][0], LDB(24 + h * 2 + 0), vacc);
      vacc = MFMA16(ta[s][1], LDB(24 + h * 2 + 1), vacc);
      of += lgh[s] * vacc;
    }
#pragma unroll
    for (int r = 0; r < 4; ++r){
      int row = (g << 2) + r;
      o_ws[row * 64 + ((h * 16 + cl) ^ ((row & 7) << 3))] = (unsigned short)f2bf(of[r]);
    }
  }
  asm volatile("s_waitcnt lgkmcnt(0)" ::: "memory");   // wave-private O complete

  // -------- phase C: out = O @ wo + bo, gated; direct f32 stores --------
  {
    bf16x8 oa[2];
#pragma unroll
    for (int ks = 0; ks < 2; ++ks)
      oa[ks] = *reinterpret_cast<const bf16x8*>(
          o_ws + cl * 64 + ((ks * 32 + g * 8) ^ ((cl & 7) << 3)));

    float* outg = out + ((size_t)i * NRES + r0) * CZ;
#pragma unroll
    for (int nt = 0; nt < 8; ++nt){
      f32x4 acc = {0.f, 0.f, 0.f, 0.f};
      acc = MFMA16(oa[0], LDB(32 + nt * 2 + 0), acc);
      acc = MFMA16(oa[1], LDB(32 + nt * 2 + 1), acc);
      int col = nt * 16 + cl;
      float bov = bo[col];
#pragma unroll
      for (int r = 0; r < 4; ++r)
        outg[(size_t)((g << 2) + r) * CZ + col] = (acc[r] + bov) * gate;
    }
  }
}

extern "C" void kernel_launch(void* const* d_in, const int* in_sizes, int n_in,
                              void* d_out, int out_size, void* d_ws, size_t ws_size,
                              hipStream_t stream) {
  const float* t    = (const float*)d_in[0];
  const float* z    = (const float*)d_in[1];
  const float* mask = (const float*)d_in[2];
  const float* wq   = (const float*)d_in[3];
  const float* wk   = (const float*)d_in[4];
  const float* wv   = (const float*)d_in[5];
  const float* wo   = (const float*)d_in[6];
  const float* bo   = (const float*)d_in[7];
  unsigned short* packed = (unsigned short*)d_ws;

  hipLaunchKernelGGL(prep_pack, dim3(12), dim3(256), 0, stream, wq, wk, wv, wo, packed);
  hipLaunchKernelGGL(tpa_main, dim3(4096), dim3(256), 0, stream,
                     t, z, mask, bo, packed, (float*)d_out);
}